// Round 2
// baseline (132.567 us; speedup 1.0000x reference)
//
#include <hip/hip_runtime.h>
#include <hip/hip_fp16.h>

// Problem constants (B,C,D,H,W) = (2,4,96,160,160)
#define NB 2
#define NC 4
#define ND 96
#define NH 160
#define NW 160

// Math (verified exact rounds 1-7): sy == sz (identical 2D 3x3 kernels),
// depth padding adds only zero slices, sobel(p)-sobel(t) = sobel(q) with
// q = softmax(pred) - onehot(target):
//   loss = sum(gx^2 + 2*gy^2) * SCALE
// separable: d = q[x+1]-q[x-1], s = q[x-1]+2q[x]+q[x+1],
//            gx = d[y-1]+2d[y]+d[y+1], gy = s[y+1]-s[y-1].
//
// Perf history:
//  r4/r5: __launch_bounds__(256,6) VGPR cap -> 128 MB scratch spill. NEVER
//         add an occupancy floor here.
//  r2..r6: same-address atomicAdds serialize cross-XCD (~20ns each). NEVER
//         one-atomic-per-block; plain per-block stores + tiny reduce kernel.
//  r8:    fp16-packed LDS class-pair planes, conflict-free b128 staging.
//  r9:    TH 8->10 (-5 MB halo) + XCD-chunked swizzle: BOTH NEUTRAL
//         (129.4 -> 130.3). Conclusion: boundary is not byte-bound; the
//         timed region is 2x300MiB harness poison fills (~94us, untouchable)
//         + our ~35us, and the boundary kernel leaves VMEM idle during its
//         compute phases (load burst -> long softmax/Sobel with zero VMEM
//         issue; ~4 blocks/CU in lockstep generations -> phase-locked
//         bubbles).
//  r10 (this): in-block software pipeline. Each block = 2 bands (20 rows)
//         over a 12-row LDS ring; next band's 10 rows are loaded to
//         REGISTERS before the current band's Sobel and stored to LDS after
//         it -> VMEM stays busy through compute. Side effect: halo 1.2x ->
//         1.1x (118 -> 108 MB). Prefetch regs not live during prologue
//         burst, so VGPR band (<=128) should hold.
constexpr int TH    = 10;             // output rows per window step
constexpr int SR    = TH + 2;         // 12-row LDS ring (vertical halo 2)
constexpr int KIT   = 2;              // windows per block
constexpr int RB    = TH * KIT;       // 20 output rows per block
constexpr int NGRP  = NH / RB;        // 8 row-groups per slice
constexpr int NBLK  = NGRP * NB * ND; // 1536 blocks / partials
constexpr int NSLOT0 = SR * NW / 4;   // 480 initial 4-px staging slots
constexpr int NSLOTR = TH * NW / 4;   // 400 restage slots
constexpr int PCELL = SR * NW;        // 1920 px cells per plane
constexpr int ZCELL = PCELL;          // always-zero guard cell (x-boundary)
constexpr int NXCD  = 8;
constexpr int CHUNK = NBLK / NXCD;    // 192 (NBLK % 8 == 0 -> bijective)
constexpr float SCALE = 1.0f / (2.0f * 98.0f * 162.0f * 162.0f * 4.0f);

__device__ __forceinline__ __half2 ld_h2(const unsigned int* p, int i) {
    return __builtin_bit_cast(__half2, p[i]);
}

// One pixel: softmax over 4 class logits minus onehot(target), packed as
// two half2 (classes 01 -> a, classes 23 -> b).
__device__ __forceinline__ void qcalc(float p0, float p1, float p2, float p3,
                                      int t, bool valid,
                                      unsigned int& ha, unsigned int& hb) {
    float q0 = 0.f, q1 = 0.f, q2 = 0.f, q3 = 0.f;
    if (valid) {
        const float m  = fmaxf(fmaxf(p0, p1), fmaxf(p2, p3));
        const float e0 = __expf(p0 - m);
        const float e1 = __expf(p1 - m);
        const float e2 = __expf(p2 - m);
        const float e3 = __expf(p3 - m);
        const float inv = 1.0f / (e0 + e1 + e2 + e3);
        q0 = e0 * inv - (t == 0 ? 1.f : 0.f);
        q1 = e1 * inv - (t == 1 ? 1.f : 0.f);
        q2 = e2 * inv - (t == 2 ? 1.f : 0.f);
        q3 = e3 * inv - (t == 3 ? 1.f : 0.f);
    }
    ha = __builtin_bit_cast(unsigned int, __floats2half2_rn(q0, q1));
    hb = __builtin_bit_cast(unsigned int, __floats2half2_rn(q2, q3));
}

// Rolling vertical Sobel over one SR-row ring window starting at LDS row
// `base` (compile-time 0 or 10 after inlining -> all addresses fold).
// Caller guarantees tid < NW.
__device__ __forceinline__ void sobel_win(const unsigned int* pa,
                                          const unsigned int* pb,
                                          int tid, int base, float& acc) {
    const bool lok = tid > 0, rok = tid < NW - 1;
    const __half2 two = __floats2half2_rn(2.f, 2.f);
    const __half2 hz  = __floats2half2_rn(0.f, 0.f);
    __half2 smmA = hz, smA = hz, dmmA = hz, dmA = hz;
    __half2 smmB = hz, smB = hz, dmmB = hz, dmB = hz;
    int rr = base;
    #pragma unroll
    for (int t = 0; t < SR; ++t) {
        const int am = rr * NW + tid;
        const int al = lok ? am - 1 : ZCELL;
        const int ar = rok ? am + 1 : ZCELL;
        {   // classes 0,1
            const __half2 l = ld_h2(pa, al);
            const __half2 m = ld_h2(pa, am);
            const __half2 r = ld_h2(pa, ar);
            const __half2 sn = __hadd2(__hfma2(m, two, l), r);
            const __half2 dn = __hsub2(r, l);
            if (t >= 2) {
                const __half2 gx = __hadd2(__hfma2(dmA, two, dmmA), dn);
                const __half2 gy = __hsub2(sn, smmA);
                const __half2 rs = __hfma2(__hmul2(gy, gy), two,
                                           __hmul2(gx, gx));
                acc += __low2float(rs) + __high2float(rs);
            }
            smmA = smA; smA = sn; dmmA = dmA; dmA = dn;
        }
        {   // classes 2,3
            const __half2 l = ld_h2(pb, al);
            const __half2 m = ld_h2(pb, am);
            const __half2 r = ld_h2(pb, ar);
            const __half2 sn = __hadd2(__hfma2(m, two, l), r);
            const __half2 dn = __hsub2(r, l);
            if (t >= 2) {
                const __half2 gx = __hadd2(__hfma2(dmB, two, dmmB), dn);
                const __half2 gy = __hsub2(sn, smmB);
                const __half2 rs = __hfma2(__hmul2(gy, gy), two,
                                           __hmul2(gx, gx));
                acc += __low2float(rs) + __high2float(rs);
            }
            smmB = smB; smB = sn; dmmB = dmB; dmB = dn;
        }
        rr = (rr + 1 == SR) ? 0 : rr + 1;
    }
}

__global__ __launch_bounds__(256) void boundary_loss_kernel(
    const float* __restrict__ pred,   // (B,C,D,H,W) f32
    const int*   __restrict__ target, // (B,D,H,W) i32
    float* __restrict__ part)         // NBLK per-block partials
{
    __shared__ unsigned int pa[PCELL + 4];  // classes 0,1 packed half2
    __shared__ unsigned int pb[PCELL + 4];  // classes 2,3 packed half2
    __shared__ float wsum[4];

    const int tid = threadIdx.x;

    // XCD-chunked swizzle (neutral in r9 but harmless; keeps vertical
    // neighbors of a slice on one XCD's L2).
    const int lin   = blockIdx.x;
    const int lin2  = (lin & (NXCD - 1)) * CHUNK + (lin >> 3);
    const int grp   = lin2 & (NGRP - 1);
    const int slice = lin2 >> 3;      // b*ND + d
    const int b     = slice / ND;
    const int d     = slice - b * ND;
    const int y0    = grp * RB;       // first output row of this block

    const size_t cs4   = (size_t)ND * NH * NW / 4;   // class stride in float4
    const size_t pbase = ((size_t)b * NC * ND + d) * (size_t)(NH * NW);
    const size_t tbase = ((size_t)b * ND + d) * (size_t)(NH * NW);

    // ======== Prologue: stage window 0 (LDS rows 0..11 = gy y0-1..y0+10) ==
    {
        const int  rA   = tid / 40;
        const int  cA   = tid - rA * 40;
        const int  gyA  = y0 - 1 + rA;
        const bool vA   = (gyA >= 0) && (gyA < NH);
        const int  gyAc = min(max(gyA, 0), NH - 1);

        const int  sB   = tid + 256;
        const bool hasB = (sB < NSLOT0);          // tid < 224
        const int  rB   = sB / 40;
        const int  cB   = sB - rB * 40;
        const int  gyB  = y0 - 1 + rB;
        const bool vB   = hasB && (gyB < NH);     // gyB >= 5 always
        const int  gyBc = min(gyB, NH - 1);

        const float4* ppA = (const float4*)(pred + pbase + (size_t)gyAc * NW) + cA;
        const float4 a0 = ppA[0];
        const float4 a1 = ppA[cs4];
        const float4 a2 = ppA[2 * cs4];
        const float4 a3 = ppA[3 * cs4];
        const int4   ta = ((const int4*)(target + tbase + (size_t)gyAc * NW))[cA];

        const int cBs  = hasB ? cB : 0;
        const int gyBs = hasB ? gyBc : 0;
        const float4* ppB = (const float4*)(pred + pbase + (size_t)gyBs * NW) + cBs;
        const float4 b0 = ppB[0];
        const float4 b1 = ppB[cs4];
        const float4 b2 = ppB[2 * cs4];
        const float4 b3 = ppB[3 * cs4];
        const int4   tb = ((const int4*)(target + tbase + (size_t)gyBs * NW))[cBs];

        {
            uint4 wa, wb;
            qcalc(a0.x, a1.x, a2.x, a3.x, ta.x, vA, wa.x, wb.x);
            qcalc(a0.y, a1.y, a2.y, a3.y, ta.y, vA, wa.y, wb.y);
            qcalc(a0.z, a1.z, a2.z, a3.z, ta.z, vA, wa.z, wb.z);
            qcalc(a0.w, a1.w, a2.w, a3.w, ta.w, vA, wa.w, wb.w);
            ((uint4*)pa)[rA * 40 + cA] = wa;   // 16-B lane stride: conflict-free
            ((uint4*)pb)[rA * 40 + cA] = wb;
        }
        if (hasB) {
            uint4 wa, wb;
            qcalc(b0.x, b1.x, b2.x, b3.x, tb.x, vB, wa.x, wb.x);
            qcalc(b0.y, b1.y, b2.y, b3.y, tb.y, vB, wa.y, wb.y);
            qcalc(b0.z, b1.z, b2.z, b3.z, tb.z, vB, wa.z, wb.z);
            qcalc(b0.w, b1.w, b2.w, b3.w, tb.w, vB, wa.w, wb.w);
            ((uint4*)pa)[rB * 40 + cB] = wa;
            ((uint4*)pb)[rB * 40 + cB] = wb;
        }
    }
    if (tid == 0) { pa[ZCELL] = 0u; pb[ZCELL] = 0u; }  // x-boundary guard
    __syncthreads();

    // ======== Prefetch window 1's 10 new rows to REGISTERS ================
    // Restage slots: 400. Slot A = tid (j = 0..6), slot B = tid+256 (tid<144,
    // j = 6..9). LDS target row j holds gy = y0 + TH + 1 + j. These loads
    // stay in flight across the window-0 Sobel below.
    const int  jA    = tid / 40;
    const int  cA2   = tid - jA * 40;
    const int  gyPA  = y0 + TH + 1 + jA;           // <= 157, always >= 11
    const bool vPA   = gyPA < NH;
    const int  gyPAc = min(gyPA, NH - 1);

    const int  sB2   = tid + 256;
    const bool hasB2 = (sB2 < NSLOTR);             // tid < 144
    const int  jB    = sB2 / 40;
    const int  cB2   = sB2 - jB * 40;
    const int  gyPB  = y0 + TH + 1 + jB;
    const bool vPB   = hasB2 && (gyPB < NH);
    const int  gyPBc = hasB2 ? min(gyPB, NH - 1) : 0;
    const int  cB2s  = hasB2 ? cB2 : 0;

    const float4* qpA = (const float4*)(pred + pbase + (size_t)gyPAc * NW) + cA2;
    const float4 A0 = qpA[0];
    const float4 A1 = qpA[cs4];
    const float4 A2 = qpA[2 * cs4];
    const float4 A3 = qpA[3 * cs4];
    const int4   tA = ((const int4*)(target + tbase + (size_t)gyPAc * NW))[cA2];

    const float4* qpB = (const float4*)(pred + pbase + (size_t)gyPBc * NW) + cB2s;
    const float4 B0 = qpB[0];
    const float4 B1 = qpB[cs4];
    const float4 B2 = qpB[2 * cs4];
    const float4 B3 = qpB[3 * cs4];
    const int4   tB = ((const int4*)(target + tbase + (size_t)gyPBc * NW))[cB2s];

    // ======== Window 0 Sobel (LDS rows 0..11), loads in flight ============
    float acc = 0.f;
    if (tid < NW) sobel_win(pa, pb, tid, 0, acc);
    __syncthreads();   // all reads of rows 0..9 done -> safe to overwrite

    // ======== Restage: qcalc prefetched regs -> LDS rows 0..9 =============
    {
        uint4 wa, wb;
        qcalc(A0.x, A1.x, A2.x, A3.x, tA.x, vPA, wa.x, wb.x);
        qcalc(A0.y, A1.y, A2.y, A3.y, tA.y, vPA, wa.y, wb.y);
        qcalc(A0.z, A1.z, A2.z, A3.z, tA.z, vPA, wa.z, wb.z);
        qcalc(A0.w, A1.w, A2.w, A3.w, tA.w, vPA, wa.w, wb.w);
        ((uint4*)pa)[jA * 40 + cA2] = wa;
        ((uint4*)pb)[jA * 40 + cA2] = wb;
    }
    if (hasB2) {
        uint4 wa, wb;
        qcalc(B0.x, B1.x, B2.x, B3.x, tB.x, vPB, wa.x, wb.x);
        qcalc(B0.y, B1.y, B2.y, B3.y, tB.y, vPB, wa.y, wb.y);
        qcalc(B0.z, B1.z, B2.z, B3.z, tB.z, vPB, wa.z, wb.z);
        qcalc(B0.w, B1.w, B2.w, B3.w, tB.w, vPB, wa.w, wb.w);
        ((uint4*)pa)[jB * 40 + cB2] = wa;
        ((uint4*)pb)[jB * 40 + cB2] = wb;
    }
    __syncthreads();

    // ======== Window 1 Sobel (ring: rows 10,11,0,1,...,9) =================
    if (tid < NW) sobel_win(pa, pb, tid, TH, acc);

    // ======== Block reduction -> ONE PLAIN STORE (no atomics) =============
    #pragma unroll
    for (int off = 32; off > 0; off >>= 1)
        acc += __shfl_down(acc, off, 64);
    if ((tid & 63) == 0) wsum[tid >> 6] = acc;
    __syncthreads();
    if (tid == 0) {
        part[lin] = wsum[0] + wsum[1] + wsum[2] + wsum[3];
    }
}

__global__ __launch_bounds__(256) void reduce_partials_kernel(
    const float* __restrict__ part, float* __restrict__ out)
{
    const int tid = threadIdx.x;
    const float4* p4 = (const float4*)part;   // NBLK/4 = 384 float4
    float s = 0.f;
    {
        const float4 v = p4[tid];
        s += (v.x + v.y) + (v.z + v.w);
    }
    if (tid < NBLK / 4 - 256) {               // 128 more
        const float4 v = p4[256 + tid];
        s += (v.x + v.y) + (v.z + v.w);
    }
    #pragma unroll
    for (int off = 32; off > 0; off >>= 1)
        s += __shfl_down(s, off, 64);
    __shared__ float wsum[4];
    if ((tid & 63) == 0) wsum[tid >> 6] = s;
    __syncthreads();
    if (tid == 0)
        out[0] = (wsum[0] + wsum[1] + wsum[2] + wsum[3]) * SCALE;
}

extern "C" void kernel_launch(void* const* d_in, const int* in_sizes, int n_in,
                              void* d_out, int out_size, void* d_ws, size_t ws_size,
                              hipStream_t stream) {
    const float* pred   = (const float*)d_in[0];
    const int*   target = (const int*)d_in[1];
    float*       out    = (float*)d_out;
    float*       part   = (float*)d_ws;      // NBLK*4 = 6 KB of scratch

    boundary_loss_kernel<<<dim3(NBLK), 256, 0, stream>>>(pred, target, part);
    reduce_partials_kernel<<<1, 256, 0, stream>>>(part, out);
}